// Round 14
// baseline (1191.112 us; speedup 1.0000x reference)
//
#include <hip/hip_runtime.h>

constexpr int N_NODES = 100000;
constexpr int N_EDGES = 1600000;
constexpr int NBK  = 391;
constexpr int NBLK = 640;
constexpr int CHUNK = 2500;
constexpr int LCNT = NBK * NBLK;
constexpr int SCAN_BLKS = (LCNT + 255) / 256;
constexpr size_t NS3 = (size_t)N_NODES * 3;   // uint2 per 12-col slice

// ---------------- bf16 helpers (RNE) ----------------

__device__ __forceinline__ unsigned bf16pack(float a, float b) {
    unsigned ua = __float_as_uint(a), ub = __float_as_uint(b);
    ua += 0x7fffu + ((ua >> 16) & 1u);
    ub += 0x7fffu + ((ub >> 16) & 1u);
    return (ua >> 16) | (ub & 0xffff0000u);
}
__device__ __forceinline__ float bflo(unsigned p) { return __uint_as_float(p << 16); }
__device__ __forceinline__ float bfhi(unsigned p) { return __uint_as_float(p & 0xffff0000u); }

// packed edge: bits 0..16 = src; bits 17..31 = 15-bit weight (implicit negative)
__device__ __forceinline__ int esrc(unsigned v) { return (int)(v & 0x1FFFFu); }
__device__ __forceinline__ float ew(unsigned v) {
    return __uint_as_float(0x80000000u | ((v >> 17) << 16));
}

// ---------------- preprocessing (proven, unchanged since R6/R12) ----------------

__global__ __launch_bounds__(256) void part_count_kernel(
    const int* __restrict__ ei, int* __restrict__ cntD, int* __restrict__ cntS) {
    __shared__ int hd[NBK], hs[NBK];
    int tid = threadIdx.x;
    for (int i = tid; i < NBK; i += 256) { hd[i] = 0; hs[i] = 0; }
    __syncthreads();
    int e0 = blockIdx.x * CHUNK;
    for (int e = e0 + tid; e < e0 + CHUNK; e += 256) {
        int s = ei[e], d = ei[N_EDGES + e];
        atomicAdd(&hs[s >> 8], 1);
        atomicAdd(&hd[d >> 8], 1);
    }
    __syncthreads();
    for (int i = tid; i < NBK; i += 256) {
        cntD[i * NBLK + blockIdx.x] = hd[i];
        cntS[i * NBLK + blockIdx.x] = hs[i];
    }
}

__global__ __launch_bounds__(256) void scanA_kernel(const int* __restrict__ in,
                                                    int* __restrict__ out,
                                                    int* __restrict__ bsum, int L) {
    __shared__ int sm[256];
    int i = blockIdx.x * 256 + threadIdx.x;
    int v = (i < L) ? in[i] : 0;
    sm[threadIdx.x] = v;
    __syncthreads();
    for (int off = 1; off < 256; off <<= 1) {
        int t = (threadIdx.x >= off) ? sm[threadIdx.x - off] : 0;
        __syncthreads();
        sm[threadIdx.x] += t;
        __syncthreads();
    }
    if (i < L) out[i] = sm[threadIdx.x] - v;
    if (threadIdx.x == 255) bsum[blockIdx.x] = sm[255];
}

__global__ __launch_bounds__(1024) void scanB_kernel(int* __restrict__ bsum, int nb) {
    __shared__ int sm[1024];
    int t = threadIdx.x;
    int v = (t < nb) ? bsum[t] : 0;
    sm[t] = v;
    __syncthreads();
    for (int off = 1; off < 1024; off <<= 1) {
        int u = (t >= off) ? sm[t - off] : 0;
        __syncthreads();
        sm[t] += u;
        __syncthreads();
    }
    if (t < nb) bsum[t] = sm[t] - v;
}

__global__ __launch_bounds__(256) void scanC_kernel(int* __restrict__ out,
                                                    const int* __restrict__ bsum, int L) {
    int i = blockIdx.x * 256 + threadIdx.x;
    if (i < L) out[i] += bsum[blockIdx.x];
}

__global__ __launch_bounds__(256) void part_scatter_kernel(
    const int* __restrict__ ei, const int* __restrict__ scanD,
    const int* __restrict__ scanS, int2* __restrict__ edgepart,
    int* __restrict__ srcpart) {
    __shared__ int curD[NBK], curS[NBK];
    int tid = threadIdx.x;
    for (int i = tid; i < NBK; i += 256) {
        curD[i] = scanD[i * NBLK + blockIdx.x];
        curS[i] = scanS[i * NBLK + blockIdx.x];
    }
    __syncthreads();
    int e0 = blockIdx.x * CHUNK;
    for (int e = e0 + tid; e < e0 + CHUNK; e += 256) {
        int s = ei[e], d = ei[N_EDGES + e];
        int pd = atomicAdd(&curD[d >> 8], 1);
        edgepart[pd] = make_int2(s, d);
        int ps = atomicAdd(&curS[s >> 8], 1);
        srcpart[ps] = s;
    }
}

__global__ __launch_bounds__(256) void deg_kernel(const int* __restrict__ srcpart,
                                                  const int* __restrict__ scanS,
                                                  float* __restrict__ dis) {
    __shared__ int cnt[256];
    int b = blockIdx.x, tid = threadIdx.x;
    cnt[tid] = 0;
    __syncthreads();
    int beg = scanS[b * NBLK];
    int end = (b + 1 < NBK) ? scanS[(b + 1) * NBLK] : N_EDGES;
    for (int j = beg + tid; j < end; j += 256)
        atomicAdd(&cnt[srcpart[j] & 255], 1);
    __syncthreads();
    int node = b * 256 + tid;
    if (node < N_NODES) dis[node] = cnt[tid] > 0 ? rsqrtf((float)cnt[tid]) : 0.f;
}

__global__ __launch_bounds__(256) void csr_kernel(const int2* __restrict__ edgepart,
                                                  const int* __restrict__ scanD,
                                                  const float* __restrict__ dis,
                                                  int* __restrict__ rp,
                                                  unsigned* __restrict__ csrc) {
    __shared__ int cnt[256];
    __shared__ int lofs[256];
    __shared__ float disl[256];
    int b = blockIdx.x, tid = threadIdx.x;
    int beg = scanD[b * NBLK];
    int end = (b + 1 < NBK) ? scanD[(b + 1) * NBLK] : N_EDGES;
    int node = b * 256 + tid;
    cnt[tid] = 0;
    disl[tid] = (node < N_NODES) ? dis[node] : 0.f;
    __syncthreads();
    for (int j = beg + tid; j < end; j += 256)
        atomicAdd(&cnt[edgepart[j].y & 255], 1);
    __syncthreads();
    int v = cnt[tid];
    lofs[tid] = v;
    __syncthreads();
    for (int off = 1; off < 256; off <<= 1) {
        int t = (tid >= off) ? lofs[tid - off] : 0;
        __syncthreads();
        lofs[tid] += t;
        __syncthreads();
    }
    int myexc = lofs[tid] - v;
    if (node < N_NODES) rp[node] = beg + myexc;
    if (b == NBK - 1 && tid == 0) rp[N_NODES] = N_EDGES;
    __syncthreads();
    lofs[tid] = myexc;
    cnt[tid] = 0;
    __syncthreads();
    for (int j = beg + tid; j < end; j += 256) {
        int2 e = edgepart[j];
        int dl = e.y & 255;
        int pos = beg + lofs[dl] + atomicAdd(&cnt[dl], 1);
        unsigned u = __float_as_uint(-(dis[e.x] * disl[dl]));
        u += 0x7fffu + ((u >> 16) & 1u);
        unsigned wb = (u >> 16) & 0x7FFFu;
        csrc[pos] = (unsigned)e.x | (wb << 17);
    }
}

// pack x [N,64] f32 -> bf16 row-major (16 u64 = 128B rows)
__global__ void pack_x_kernel(const float* __restrict__ x, uint2* __restrict__ xbf) {
    int i = blockIdx.x * blockDim.x + threadIdx.x;
    if (i >= N_NODES * 16) return;
    float4 v = ((const float4*)x)[i];
    xbf[i] = make_uint2(bf16pack(v.x, v.y), bf16pack(v.z, v.w));
}

// ---------------- fused sliced Clenshaw step ----------------
// One launch handles 12 output cols (slice s). All 36-col buffers are
// slice-major [3][N][3 u64]; the gather reads a contiguous 2.4MB region that
// fits (replicated) in every XCD's 4MB L2. Proj stays fused (R11 lesson).
// OUT_s[row] = SCALE*sum_j w_j*IN_s[src_j] + A'[row]@W[:,12s:12s+12]
//              (- B2_s[row]) (+bias,relu)

template <int FI, int SCALE, bool HAS_B2, bool BN_A, bool BIAS_RELU, bool FUSE_STATS>
__global__ __launch_bounds__(256) void cstep_kernel(
    const int* __restrict__ rp, const unsigned* __restrict__ csrc,
    const uint2* __restrict__ INs, const uint2* __restrict__ B2s,
    const uint2* __restrict__ Ab, const float* __restrict__ W,
    const float* __restrict__ ss, const float* __restrict__ bias,
    unsigned long long* __restrict__ OUTs, float* __restrict__ partials, int s) {
    constexpr int RU2 = FI / 4;                  // u64 per A row
    __shared__ float Wl[FI * 12];
    __shared__ float Atile[84][FI + 1];
    __shared__ float ls[24];
    int tid = threadIdx.x;                       // 252 = 84 rows x 3 lanes
    for (int i = tid; i < FI * 12; i += 252)
        Wl[i] = W[(i / 12) * 36 + s * 12 + (i % 12)];
    int r0 = blockIdx.x * 84;
    const long long* ab8 = (const long long*)Ab;
    for (int i = tid; i < 84 * RU2; i += 252) {
        int r = i / RU2, u = i % RU2;
        int row = r0 + r;
        long long av = 0;
        if (row < N_NODES) {
            size_t idx = (FI == 64) ? ((size_t)row * 16 + u)
                                    : ((size_t)(u / 3) * NS3 + (size_t)row * 3 + (u % 3));
            av = ab8[idx];
        }
        unsigned lo = (unsigned)av, hi = (unsigned)(av >> 32);
        float f0 = bflo(lo), f1 = bfhi(lo), f2 = bflo(hi), f3 = bfhi(hi);
        if (BN_A) {
            int f = u * 4;
            f0 = fmaxf(fmaf(ss[f + 0], f0, ss[36 + f + 0]), 0.f);
            f1 = fmaxf(fmaf(ss[f + 1], f1, ss[36 + f + 1]), 0.f);
            f2 = fmaxf(fmaf(ss[f + 2], f2, ss[36 + f + 2]), 0.f);
            f3 = fmaxf(fmaf(ss[f + 3], f3, ss[36 + f + 3]), 0.f);
        }
        Atile[r][u * 4 + 0] = f0; Atile[r][u * 4 + 1] = f1;
        Atile[r][u * 4 + 2] = f2; Atile[r][u * 4 + 3] = f3;
    }
    if (FUSE_STATS && tid < 24) ls[tid] = 0.f;
    __syncthreads();
    int r = tid / 3, c = tid % 3;
    int row = r0 + r;
    bool valid = row < N_NODES;
    float ax = 0, ay = 0, az = 0, aw = 0;
    float bx = 0, by = 0, bz = 0, bw = 0;
    float cx = 0, cy = 0, cz = 0, cw = 0;
    float dx = 0, dy = 0, dz = 0, dw = 0;
    if (SCALE != 0 && valid) {
        int beg = rp[row], end = rp[row + 1];
        int j = beg;
        for (; j + 7 < end; j += 8) {
            unsigned v0 = csrc[j],     v1 = csrc[j + 1], v2 = csrc[j + 2], v3 = csrc[j + 3];
            unsigned v4 = csrc[j + 4], v5 = csrc[j + 5], v6 = csrc[j + 6], v7 = csrc[j + 7];
            uint2 u0 = INs[(size_t)esrc(v0) * 3 + c];
            uint2 u1 = INs[(size_t)esrc(v1) * 3 + c];
            uint2 u2 = INs[(size_t)esrc(v2) * 3 + c];
            uint2 u3 = INs[(size_t)esrc(v3) * 3 + c];
            uint2 u4 = INs[(size_t)esrc(v4) * 3 + c];
            uint2 u5 = INs[(size_t)esrc(v5) * 3 + c];
            uint2 u6 = INs[(size_t)esrc(v6) * 3 + c];
            uint2 u7 = INs[(size_t)esrc(v7) * 3 + c];
            float w0 = ew(v0), w1 = ew(v1), w2 = ew(v2), w3 = ew(v3);
            float w4 = ew(v4), w5 = ew(v5), w6 = ew(v6), w7 = ew(v7);
            ax = fmaf(w0, bflo(u0.x), ax); ay = fmaf(w0, bfhi(u0.x), ay);
            az = fmaf(w0, bflo(u0.y), az); aw = fmaf(w0, bfhi(u0.y), aw);
            bx = fmaf(w1, bflo(u1.x), bx); by = fmaf(w1, bfhi(u1.x), by);
            bz = fmaf(w1, bflo(u1.y), bz); bw = fmaf(w1, bfhi(u1.y), bw);
            cx = fmaf(w2, bflo(u2.x), cx); cy = fmaf(w2, bfhi(u2.x), cy);
            cz = fmaf(w2, bflo(u2.y), cz); cw = fmaf(w2, bfhi(u2.y), cw);
            dx = fmaf(w3, bflo(u3.x), dx); dy = fmaf(w3, bfhi(u3.x), dy);
            dz = fmaf(w3, bflo(u3.y), dz); dw = fmaf(w3, bfhi(u3.y), dw);
            ax = fmaf(w4, bflo(u4.x), ax); ay = fmaf(w4, bfhi(u4.x), ay);
            az = fmaf(w4, bflo(u4.y), az); aw = fmaf(w4, bfhi(u4.y), aw);
            bx = fmaf(w5, bflo(u5.x), bx); by = fmaf(w5, bfhi(u5.x), by);
            bz = fmaf(w5, bflo(u5.y), bz); bw = fmaf(w5, bfhi(u5.y), bw);
            cx = fmaf(w6, bflo(u6.x), cx); cy = fmaf(w6, bfhi(u6.x), cy);
            cz = fmaf(w6, bflo(u6.y), cz); cw = fmaf(w6, bfhi(u6.y), cw);
            dx = fmaf(w7, bflo(u7.x), dx); dy = fmaf(w7, bfhi(u7.x), dy);
            dz = fmaf(w7, bflo(u7.y), dz); dw = fmaf(w7, bfhi(u7.y), dw);
        }
        for (; j < end; ++j) {
            unsigned v = csrc[j];
            uint2 u = INs[(size_t)esrc(v) * 3 + c];
            float w = ew(v);
            ax = fmaf(w, bflo(u.x), ax); ay = fmaf(w, bfhi(u.x), ay);
            az = fmaf(w, bflo(u.y), az); aw = fmaf(w, bfhi(u.y), aw);
        }
        ax += bx + cx + dx; ay += by + cy + dy;
        az += bz + cz + dz; aw += bw + cw + dw;
    }
    float px = 0, py = 0, pz = 0, pw = 0;
    const float4* Wl4 = (const float4*)Wl;
#pragma unroll 4
    for (int f = 0; f < FI; ++f) {
        float a = Atile[r][f];
        float4 wv = Wl4[f * 3 + c];
        px = fmaf(a, wv.x, px); py = fmaf(a, wv.y, py);
        pz = fmaf(a, wv.z, pz); pw = fmaf(a, wv.w, pw);
    }
    const float S = (float)SCALE;
    float ox = fmaf(S, ax, px), oy = fmaf(S, ay, py);
    float oz = fmaf(S, az, pz), ow = fmaf(S, aw, pw);
    if (valid) {
        if (HAS_B2) {
            uint2 u = B2s[(size_t)row * 3 + c];
            ox -= bflo(u.x); oy -= bfhi(u.x);
            oz -= bflo(u.y); ow -= bfhi(u.y);
        }
        if (BIAS_RELU) {
            int cb = s * 12 + c * 4;
            ox = fmaxf(ox + bias[cb + 0], 0.f); oy = fmaxf(oy + bias[cb + 1], 0.f);
            oz = fmaxf(oz + bias[cb + 2], 0.f); ow = fmaxf(ow + bias[cb + 3], 0.f);
        }
        unsigned long long pv = (unsigned long long)bf16pack(ox, oy)
                              | ((unsigned long long)bf16pack(oz, ow) << 32);
        OUTs[(size_t)row * 3 + c] = pv;
        if (FUSE_STATS) {
            atomicAdd(&ls[c * 4 + 0], ox); atomicAdd(&ls[12 + c * 4 + 0], ox * ox);
            atomicAdd(&ls[c * 4 + 1], oy); atomicAdd(&ls[12 + c * 4 + 1], oy * oy);
            atomicAdd(&ls[c * 4 + 2], oz); atomicAdd(&ls[12 + c * 4 + 2], oz * oz);
            atomicAdd(&ls[c * 4 + 3], ow); atomicAdd(&ls[12 + c * 4 + 3], ow * ow);
        }
    }
    if (FUSE_STATS) {
        __syncthreads();
        if (tid < 12) {
            partials[(size_t)blockIdx.x * 72 + s * 12 + tid] = ls[tid];
            partials[(size_t)blockIdx.x * 72 + 36 + s * 12 + tid] = ls[12 + tid];
        }
    }
}

// ---------------- GIN sliced self+sum gather: m1 = relu(y_self + sum y_src + b1) ----

__global__ __launch_bounds__(256) void ginstep_kernel(
    const int* __restrict__ rp, const unsigned* __restrict__ csrc,
    const uint2* __restrict__ Ys, const float* __restrict__ b1,
    unsigned long long* __restrict__ OUTs, int s) {
    int tid = threadIdx.x;                       // 252 = 84 rows x 3 lanes
    int r = tid / 3, c = tid % 3;
    int row = blockIdx.x * 84 + r;
    if (row >= N_NODES) return;
    uint2 us = Ys[(size_t)row * 3 + c];
    float ax = bflo(us.x), ay = bfhi(us.x), az = bflo(us.y), aw = bfhi(us.y);
    float bx = 0, by = 0, bz = 0, bw = 0;
    float cx = 0, cy = 0, cz = 0, cw = 0;
    float dx = 0, dy = 0, dz = 0, dw = 0;
    int beg = rp[row], end = rp[row + 1];
    int j = beg;
    for (; j + 7 < end; j += 8) {
        int s0 = esrc(csrc[j]),     s1 = esrc(csrc[j + 1]);
        int s2 = esrc(csrc[j + 2]), s3 = esrc(csrc[j + 3]);
        int s4 = esrc(csrc[j + 4]), s5 = esrc(csrc[j + 5]);
        int s6 = esrc(csrc[j + 6]), s7 = esrc(csrc[j + 7]);
        uint2 u0 = Ys[(size_t)s0 * 3 + c];
        uint2 u1 = Ys[(size_t)s1 * 3 + c];
        uint2 u2 = Ys[(size_t)s2 * 3 + c];
        uint2 u3 = Ys[(size_t)s3 * 3 + c];
        uint2 u4 = Ys[(size_t)s4 * 3 + c];
        uint2 u5 = Ys[(size_t)s5 * 3 + c];
        uint2 u6 = Ys[(size_t)s6 * 3 + c];
        uint2 u7 = Ys[(size_t)s7 * 3 + c];
        ax += bflo(u0.x) + bflo(u4.x); ay += bfhi(u0.x) + bfhi(u4.x);
        az += bflo(u0.y) + bflo(u4.y); aw += bfhi(u0.y) + bfhi(u4.y);
        bx += bflo(u1.x) + bflo(u5.x); by += bfhi(u1.x) + bfhi(u5.x);
        bz += bflo(u1.y) + bflo(u5.y); bw += bfhi(u1.y) + bfhi(u5.y);
        cx += bflo(u2.x) + bflo(u6.x); cy += bfhi(u2.x) + bfhi(u6.x);
        cz += bflo(u2.y) + bflo(u6.y); cw += bfhi(u2.y) + bfhi(u6.y);
        dx += bflo(u3.x) + bflo(u7.x); dy += bfhi(u3.x) + bfhi(u7.x);
        dz += bflo(u3.y) + bflo(u7.y); dw += bfhi(u3.y) + bfhi(u7.y);
    }
    for (; j < end; ++j) {
        uint2 u = Ys[(size_t)esrc(csrc[j]) * 3 + c];
        ax += bflo(u.x); ay += bfhi(u.x);
        az += bflo(u.y); aw += bfhi(u.y);
    }
    ax += bx + cx + dx; ay += by + cy + dy;
    az += bz + cz + dz; aw += bw + cw + dw;
    int cb = s * 12 + c * 4;
    ax = fmaxf(ax + b1[cb + 0], 0.f); ay = fmaxf(ay + b1[cb + 1], 0.f);
    az = fmaxf(az + b1[cb + 2], 0.f); aw = fmaxf(aw + b1[cb + 3], 0.f);
    unsigned long long pv = (unsigned long long)bf16pack(ax, ay)
                          | ((unsigned long long)bf16pack(az, aw) << 32);
    OUTs[(size_t)row * 3 + c] = pv;
}

// ---------------- finalize: reduce partials -> BN scale/shift ----------------

__global__ __launch_bounds__(256) void finalize_kernel(
    const float* __restrict__ partials, int nb, const float* __restrict__ g,
    const float* __restrict__ be, float* __restrict__ ss) {
    __shared__ float rs[256], rq[256];
    int c = blockIdx.x;
    int t = threadIdx.x;
    float s = 0.f, q = 0.f;
    for (int i = t; i < nb; i += 256) {
        s += partials[(size_t)i * 72 + c];
        q += partials[(size_t)i * 72 + c + 36];
    }
    rs[t] = s; rq[t] = q;
    __syncthreads();
    for (int off = 128; off > 0; off >>= 1) {
        if (t < off) { rs[t] += rs[t + off]; rq[t] += rq[t + off]; }
        __syncthreads();
    }
    if (t == 0) {
        float m = rs[0] / (float)N_NODES;
        float v = rq[0] / (float)N_NODES - m * m;
        float sc = g[c] * rsqrtf(v + 1e-5f);
        ss[c] = sc;
        ss[36 + c] = be[c] - m * sc;
    }
}

// ---------------- final concat GEMM, bf16 slice-major inputs ----------------

__global__ __launch_bounds__(256) void fused3_kernel(
    const uint2* __restrict__ X1b, const float* __restrict__ ssA,
    const uint2* __restrict__ X2b, const float* __restrict__ ssB,
    const uint2* __restrict__ X3b, const float* __restrict__ ssC,
    const float* __restrict__ W, const float* __restrict__ b,
    float* __restrict__ out) {
    __shared__ float Wl[108 * 32];
    __shared__ float Al[32][109];
    int tid = threadIdx.x;
    for (int i = tid; i < 108 * 32; i += 256) Wl[i] = W[i];
    int r0 = blockIdx.x * 32;
    for (int i = tid; i < 32 * 108; i += 256) {
        int r = i / 108, f = i % 108;
        int row = r0 + r;
        float v = 0.f;
        if (row < N_NODES) {
            int t = f / 36, ff = f % 36, sl = ff / 12, w = ff % 12;
            const uint2* base = (t == 0 ? X1b : (t == 1 ? X2b : X3b)) + (size_t)sl * NS3;
            unsigned short u16 = ((const unsigned short*)base)[(size_t)row * 12 + w];
            float xv = __uint_as_float((unsigned)u16 << 16);
            if (t == 0)      v = fmaxf(fmaf(ssA[ff], xv, ssA[36 + ff]), 0.f);
            else if (t == 1) v = fmaxf(fmaf(ssB[ff], xv, ssB[36 + ff]), 0.f);
            else             v = fmaf(ssC[ff], xv, ssC[36 + ff]);
        }
        Al[r][f] = v;
    }
    __syncthreads();
    int r = tid >> 3, q = tid & 7;
    int row = r0 + r;
    if (row >= N_NODES) return;
    float acc[4];
#pragma unroll
    for (int j = 0; j < 4; ++j) acc[j] = b[q * 4 + j];
    for (int f = 0; f < 108; ++f) {
        float a = Al[r][f];
#pragma unroll
        for (int j = 0; j < 4; ++j)
            acc[j] = fmaf(a, Wl[f * 32 + q * 4 + j], acc[j]);
    }
#pragma unroll
    for (int j = 0; j < 4; ++j) out[(size_t)row * 32 + q * 4 + j] = acc[j];
}

// ---------------- launch ----------------

extern "C" void kernel_launch(void* const* d_in, const int* in_sizes, int n_in,
                              void* d_out, int out_size, void* d_ws, size_t ws_size,
                              hipStream_t stream) {
    const float* x      = (const float*)d_in[0];
    const int*   ei     = (const int*)d_in[1];
    const float* W1_1   = (const float*)d_in[2];
    // b1_1 / b1_2 cancel exactly under training-mode BN -> dropped.
    const float* g1_1   = (const float*)d_in[4];
    const float* be1_1  = (const float*)d_in[5];
    const float* W1_2   = (const float*)d_in[6];
    const float* g1_2   = (const float*)d_in[8];
    const float* be1_2  = (const float*)d_in[9];
    const float* gin_w1 = (const float*)d_in[10];
    const float* gin_b1 = (const float*)d_in[11];
    const float* gin_w2 = (const float*)d_in[12];
    const float* gin_b2 = (const float*)d_in[13];
    const float* g2     = (const float*)d_in[14];
    const float* be2    = (const float*)d_in[15];
    const float* W4     = (const float*)d_in[16];
    const float* b4     = (const float*)d_in[17];
    float* out = (float*)d_out;

    char* ws = (char*)d_ws;
    size_t off = 0;
    auto alloc = [&](size_t bytes) -> char* {
        char* p = ws + off;
        off = (off + bytes + 255) & ~(size_t)255;
        return p;
    };
    int*   cntD  = (int*)alloc((size_t)LCNT * 4);
    int*   cntS  = (int*)alloc((size_t)LCNT * 4);
    int*   bsum  = (int*)alloc(1024 * 4);
    int*   rp    = (int*)alloc((size_t)(N_NODES + 1) * 4);
    float* dis   = (float*)alloc((size_t)N_NODES * 4);
    int2*  edgepart = (int2*)alloc((size_t)N_EDGES * 8);
    int*   srcpart  = (int*)alloc((size_t)N_EDGES * 4);
    unsigned* csrc = (unsigned*)alloc((size_t)N_EDGES * 4);
    float* ssA   = (float*)alloc(72 * 4);
    float* ssB   = (float*)alloc(72 * 4);
    float* ssC   = (float*)alloc(72 * 4);
    float* partials = (float*)alloc((size_t)4096 * 72 * 4);
    constexpr size_t NBBF = NS3 * 3 * 8;                   // 7.2MB slice-major buffer
    uint2* xbf = (uint2*)alloc((size_t)N_NODES * 128);     // bf16 [N,64] 128B rows
    uint2* R0  = (uint2*)alloc(NBBF);
    uint2* R1  = (uint2*)alloc(NBBF);
    uint2* R2  = (uint2*)alloc(NBBF);
    uint2* X1b = (uint2*)alloc(NBBF);
    uint2* X2b = (uint2*)alloc(NBBF);
    uint2* X3b = (uint2*)alloc(NBBF);
    if (off > ws_size) return;

    // ---- preprocessing: counting-sort CSR build (no global atomics) ----
    part_count_kernel<<<NBLK, 256, 0, stream>>>(ei, cntD, cntS);
    scanA_kernel<<<SCAN_BLKS, 256, 0, stream>>>(cntD, cntD, bsum, LCNT);
    scanB_kernel<<<1, 1024, 0, stream>>>(bsum, SCAN_BLKS);
    scanC_kernel<<<SCAN_BLKS, 256, 0, stream>>>(cntD, bsum, LCNT);
    scanA_kernel<<<SCAN_BLKS, 256, 0, stream>>>(cntS, cntS, bsum, LCNT);
    scanB_kernel<<<1, 1024, 0, stream>>>(bsum, SCAN_BLKS);
    scanC_kernel<<<SCAN_BLKS, 256, 0, stream>>>(cntS, bsum, LCNT);
    part_scatter_kernel<<<NBLK, 256, 0, stream>>>(ei, cntD, cntS, edgepart, srcpart);
    deg_kernel<<<NBK, 256, 0, stream>>>(srcpart, cntS, dis);
    csr_kernel<<<NBK, 256, 0, stream>>>(edgepart, cntD, dis, rp, csrc);
    pack_x_kernel<<<(N_NODES * 16 + 255) / 256, 256, 0, stream>>>(x, xbf);

    const int GBLKS = (N_NODES + 83) / 84;   // 1191
    const int F3_BLKS = (N_NODES + 31) / 32; // 3125

    auto SL  = [&](uint2* p, int s) { return (const uint2*)(p + (size_t)s * NS3); };
    auto SLO = [&](uint2* p, int s) { return (unsigned long long*)(p + (size_t)s * NS3); };

    // ---- conv1_1 (sliced Clenshaw, FI=64, A=xbf) ----
    for (int s = 0; s < 3; ++s) {
        cstep_kernel<64, 0, false, false, false, false><<<GBLKS, 252, 0, stream>>>(
            rp, csrc, nullptr, nullptr, xbf, W1_1 + 7 * 2304, nullptr, nullptr, SLO(R0, s), nullptr, s);
        cstep_kernel<64, 2, false, false, false, false><<<GBLKS, 252, 0, stream>>>(
            rp, csrc, SL(R0, s), nullptr, xbf, W1_1 + 6 * 2304, nullptr, nullptr, SLO(R1, s), nullptr, s);
        cstep_kernel<64, 2, true, false, false, false><<<GBLKS, 252, 0, stream>>>(
            rp, csrc, SL(R1, s), SL(R0, s), xbf, W1_1 + 5 * 2304, nullptr, nullptr, SLO(R2, s), nullptr, s);
        cstep_kernel<64, 2, true, false, false, false><<<GBLKS, 252, 0, stream>>>(
            rp, csrc, SL(R2, s), SL(R1, s), xbf, W1_1 + 4 * 2304, nullptr, nullptr, SLO(R0, s), nullptr, s);
        cstep_kernel<64, 2, true, false, false, false><<<GBLKS, 252, 0, stream>>>(
            rp, csrc, SL(R0, s), SL(R2, s), xbf, W1_1 + 3 * 2304, nullptr, nullptr, SLO(R1, s), nullptr, s);
        cstep_kernel<64, 2, true, false, false, false><<<GBLKS, 252, 0, stream>>>(
            rp, csrc, SL(R1, s), SL(R0, s), xbf, W1_1 + 2 * 2304, nullptr, nullptr, SLO(R2, s), nullptr, s);
        cstep_kernel<64, 2, true, false, false, false><<<GBLKS, 252, 0, stream>>>(
            rp, csrc, SL(R2, s), SL(R1, s), xbf, W1_1 + 1 * 2304, nullptr, nullptr, SLO(R0, s), nullptr, s);
        cstep_kernel<64, 1, true, false, false, true><<<GBLKS, 252, 0, stream>>>(
            rp, csrc, SL(R0, s), SL(R2, s), xbf, W1_1 + 0 * 2304, nullptr, nullptr, SLO(X1b, s), partials, s);
    }
    finalize_kernel<<<36, 256, 0, stream>>>(partials, GBLKS, g1_1, be1_1, ssA);

    // ---- conv1_2 (sliced Clenshaw, FI=36, A=X1b with BN ssA) ----
    for (int s = 0; s < 3; ++s) {
        cstep_kernel<36, 0, false, true, false, false><<<GBLKS, 252, 0, stream>>>(
            rp, csrc, nullptr, nullptr, X1b, W1_2 + 7 * 1296, ssA, nullptr, SLO(R0, s), nullptr, s);
        cstep_kernel<36, 2, false, true, false, false><<<GBLKS, 252, 0, stream>>>(
            rp, csrc, SL(R0, s), nullptr, X1b, W1_2 + 6 * 1296, ssA, nullptr, SLO(R1, s), nullptr, s);
        cstep_kernel<36, 2, true, true, false, false><<<GBLKS, 252, 0, stream>>>(
            rp, csrc, SL(R1, s), SL(R0, s), X1b, W1_2 + 5 * 1296, ssA, nullptr, SLO(R2, s), nullptr, s);
        cstep_kernel<36, 2, true, true, false, false><<<GBLKS, 252, 0, stream>>>(
            rp, csrc, SL(R2, s), SL(R1, s), X1b, W1_2 + 4 * 1296, ssA, nullptr, SLO(R0, s), nullptr, s);
        cstep_kernel<36, 2, true, true, false, false><<<GBLKS, 252, 0, stream>>>(
            rp, csrc, SL(R0, s), SL(R2, s), X1b, W1_2 + 3 * 1296, ssA, nullptr, SLO(R1, s), nullptr, s);
        cstep_kernel<36, 2, true, true, false, false><<<GBLKS, 252, 0, stream>>>(
            rp, csrc, SL(R1, s), SL(R0, s), X1b, W1_2 + 2 * 1296, ssA, nullptr, SLO(R2, s), nullptr, s);
        cstep_kernel<36, 2, true, true, false, false><<<GBLKS, 252, 0, stream>>>(
            rp, csrc, SL(R2, s), SL(R1, s), X1b, W1_2 + 1 * 1296, ssA, nullptr, SLO(R0, s), nullptr, s);
        cstep_kernel<36, 1, true, true, false, true><<<GBLKS, 252, 0, stream>>>(
            rp, csrc, SL(R0, s), SL(R2, s), X1b, W1_2 + 0 * 1296, ssA, nullptr, SLO(X2b, s), partials, s);
    }
    finalize_kernel<<<36, 256, 0, stream>>>(partials, GBLKS, g1_2, be1_2, ssB);

    // ---- GIN: y = x@w1 (sliced proj); m1 = relu(y+Σy+b1); X3 = relu(m1@w2+b2)+stats ----
    for (int s = 0; s < 3; ++s)
        cstep_kernel<64, 0, false, false, false, false><<<GBLKS, 252, 0, stream>>>(
            rp, csrc, nullptr, nullptr, xbf, gin_w1, nullptr, nullptr, SLO(R0, s), nullptr, s);
    for (int s = 0; s < 3; ++s)
        ginstep_kernel<<<GBLKS, 252, 0, stream>>>(rp, csrc, SL(R0, s), gin_b1, SLO(R1, s), s);
    for (int s = 0; s < 3; ++s)
        cstep_kernel<36, 0, false, false, true, true><<<GBLKS, 252, 0, stream>>>(
            rp, csrc, nullptr, nullptr, R1, gin_w2, nullptr, gin_b2, SLO(X3b, s), partials, s);
    finalize_kernel<<<36, 256, 0, stream>>>(partials, GBLKS, g2, be2, ssC);

    // ---- final concat GEMM ----
    fused3_kernel<<<F3_BLKS, 256, 0, stream>>>(X1b, ssA, X2b, ssB, X3b, ssC, W4, b4, out);
}

// Round 15
// 906.751 us; speedup vs baseline: 1.3136x; 1.3136x over previous
//
#include <hip/hip_runtime.h>

constexpr int N_NODES = 100000;
constexpr int N_EDGES = 1600000;
constexpr int NBK  = 391;
constexpr int NBLK = 640;
constexpr int CHUNK = 2500;
constexpr int LCNT = NBK * NBLK;
constexpr int SCAN_BLKS = (LCNT + 255) / 256;

// ---------------- bf16 helpers (RNE) ----------------

__device__ __forceinline__ unsigned bf16pack(float a, float b) {
    unsigned ua = __float_as_uint(a), ub = __float_as_uint(b);
    ua += 0x7fffu + ((ua >> 16) & 1u);
    ub += 0x7fffu + ((ub >> 16) & 1u);
    return (ua >> 16) | (ub & 0xffff0000u);
}
__device__ __forceinline__ float bflo(unsigned p) { return __uint_as_float(p << 16); }
__device__ __forceinline__ float bfhi(unsigned p) { return __uint_as_float(p & 0xffff0000u); }

// packed edge: bits 0..16 = src; bits 17..31 = 15-bit weight (implicit negative)
__device__ __forceinline__ int esrc(unsigned v) { return (int)(v & 0x1FFFFu); }
__device__ __forceinline__ float ew(unsigned v) {
    return __uint_as_float(0x80000000u | ((v >> 17) << 16));
}

// Split bf16 36-col buffer layout (sector-aligned gather):
//   A-region: [N][8 u64]  (cols 0..31, 64B-aligned rows -> 1 sector/gather)
//   B-region: [N][1 u64]  (cols 32..35) at u64 offset N*8  (0.8MB, L2-hot)
// lane c in 0..8: u64 index = (c<8) ? row*8+c : N*8+row
__device__ __forceinline__ size_t sidx(int c, int row) {
    return (c < 8) ? ((size_t)row * 8 + c) : ((size_t)N_NODES * 8 + row);
}

// ---------------- preprocessing (proven, unchanged) ----------------

__global__ __launch_bounds__(256) void part_count_kernel(
    const int* __restrict__ ei, int* __restrict__ cntD, int* __restrict__ cntS) {
    __shared__ int hd[NBK], hs[NBK];
    int tid = threadIdx.x;
    for (int i = tid; i < NBK; i += 256) { hd[i] = 0; hs[i] = 0; }
    __syncthreads();
    int e0 = blockIdx.x * CHUNK;
    for (int e = e0 + tid; e < e0 + CHUNK; e += 256) {
        int s = ei[e], d = ei[N_EDGES + e];
        atomicAdd(&hs[s >> 8], 1);
        atomicAdd(&hd[d >> 8], 1);
    }
    __syncthreads();
    for (int i = tid; i < NBK; i += 256) {
        cntD[i * NBLK + blockIdx.x] = hd[i];
        cntS[i * NBLK + blockIdx.x] = hs[i];
    }
}

__global__ __launch_bounds__(256) void scanA_kernel(const int* __restrict__ in,
                                                    int* __restrict__ out,
                                                    int* __restrict__ bsum, int L) {
    __shared__ int sm[256];
    int i = blockIdx.x * 256 + threadIdx.x;
    int v = (i < L) ? in[i] : 0;
    sm[threadIdx.x] = v;
    __syncthreads();
    for (int off = 1; off < 256; off <<= 1) {
        int t = (threadIdx.x >= off) ? sm[threadIdx.x - off] : 0;
        __syncthreads();
        sm[threadIdx.x] += t;
        __syncthreads();
    }
    if (i < L) out[i] = sm[threadIdx.x] - v;
    if (threadIdx.x == 255) bsum[blockIdx.x] = sm[255];
}

__global__ __launch_bounds__(1024) void scanB_kernel(int* __restrict__ bsum, int nb) {
    __shared__ int sm[1024];
    int t = threadIdx.x;
    int v = (t < nb) ? bsum[t] : 0;
    sm[t] = v;
    __syncthreads();
    for (int off = 1; off < 1024; off <<= 1) {
        int u = (t >= off) ? sm[t - off] : 0;
        __syncthreads();
        sm[t] += u;
        __syncthreads();
    }
    if (t < nb) bsum[t] = sm[t] - v;
}

__global__ __launch_bounds__(256) void scanC_kernel(int* __restrict__ out,
                                                    const int* __restrict__ bsum, int L) {
    int i = blockIdx.x * 256 + threadIdx.x;
    if (i < L) out[i] += bsum[blockIdx.x];
}

__global__ __launch_bounds__(256) void part_scatter_kernel(
    const int* __restrict__ ei, const int* __restrict__ scanD,
    const int* __restrict__ scanS, int2* __restrict__ edgepart,
    int* __restrict__ srcpart) {
    __shared__ int curD[NBK], curS[NBK];
    int tid = threadIdx.x;
    for (int i = tid; i < NBK; i += 256) {
        curD[i] = scanD[i * NBLK + blockIdx.x];
        curS[i] = scanS[i * NBLK + blockIdx.x];
    }
    __syncthreads();
    int e0 = blockIdx.x * CHUNK;
    for (int e = e0 + tid; e < e0 + CHUNK; e += 256) {
        int s = ei[e], d = ei[N_EDGES + e];
        int pd = atomicAdd(&curD[d >> 8], 1);
        edgepart[pd] = make_int2(s, d);
        int ps = atomicAdd(&curS[s >> 8], 1);
        srcpart[ps] = s;
    }
}

__global__ __launch_bounds__(256) void deg_kernel(const int* __restrict__ srcpart,
                                                  const int* __restrict__ scanS,
                                                  float* __restrict__ dis) {
    __shared__ int cnt[256];
    int b = blockIdx.x, tid = threadIdx.x;
    cnt[tid] = 0;
    __syncthreads();
    int beg = scanS[b * NBLK];
    int end = (b + 1 < NBK) ? scanS[(b + 1) * NBLK] : N_EDGES;
    for (int j = beg + tid; j < end; j += 256)
        atomicAdd(&cnt[srcpart[j] & 255], 1);
    __syncthreads();
    int node = b * 256 + tid;
    if (node < N_NODES) dis[node] = cnt[tid] > 0 ? rsqrtf((float)cnt[tid]) : 0.f;
}

__global__ __launch_bounds__(256) void csr_kernel(const int2* __restrict__ edgepart,
                                                  const int* __restrict__ scanD,
                                                  const float* __restrict__ dis,
                                                  int* __restrict__ rp,
                                                  unsigned* __restrict__ csrc) {
    __shared__ int cnt[256];
    __shared__ int lofs[256];
    __shared__ float disl[256];
    int b = blockIdx.x, tid = threadIdx.x;
    int beg = scanD[b * NBLK];
    int end = (b + 1 < NBK) ? scanD[(b + 1) * NBLK] : N_EDGES;
    int node = b * 256 + tid;
    cnt[tid] = 0;
    disl[tid] = (node < N_NODES) ? dis[node] : 0.f;
    __syncthreads();
    for (int j = beg + tid; j < end; j += 256)
        atomicAdd(&cnt[edgepart[j].y & 255], 1);
    __syncthreads();
    int v = cnt[tid];
    lofs[tid] = v;
    __syncthreads();
    for (int off = 1; off < 256; off <<= 1) {
        int t = (tid >= off) ? lofs[tid - off] : 0;
        __syncthreads();
        lofs[tid] += t;
        __syncthreads();
    }
    int myexc = lofs[tid] - v;
    if (node < N_NODES) rp[node] = beg + myexc;
    if (b == NBK - 1 && tid == 0) rp[N_NODES] = N_EDGES;
    __syncthreads();
    lofs[tid] = myexc;
    cnt[tid] = 0;
    __syncthreads();
    for (int j = beg + tid; j < end; j += 256) {
        int2 e = edgepart[j];
        int dl = e.y & 255;
        int pos = beg + lofs[dl] + atomicAdd(&cnt[dl], 1);
        unsigned u = __float_as_uint(-(dis[e.x] * disl[dl]));
        u += 0x7fffu + ((u >> 16) & 1u);
        unsigned wb = (u >> 16) & 0x7FFFu;
        csrc[pos] = (unsigned)e.x | (wb << 17);
    }
}

// pack x [N,64] f32 -> bf16 row-major (16 u64 = 128B rows)
__global__ void pack_x_kernel(const float* __restrict__ x, uint2* __restrict__ xbf) {
    int i = blockIdx.x * blockDim.x + threadIdx.x;
    if (i >= N_NODES * 16) return;
    float4 v = ((const float4*)x)[i];
    xbf[i] = make_uint2(bf16pack(v.x, v.y), bf16pack(v.z, v.w));
}

// ---------------- fused Clenshaw step (split-layout buffers) ----------------
// OUT[row] = SCALE * sum_j w_j*INb[src_j] + A'[row]@W - (HAS_B2 ? B2b[row] : 0)
// INb/B2b/OUT: split layout (see sidx). Ab: FI=64 -> xbf 128B rows; FI=36 -> split.

template <int FI, int SCALE, bool HAS_B2, bool BN_A, bool FUSE_STATS>
__global__ __launch_bounds__(256) void cheb_step_kernel(
    const int* __restrict__ rp, const unsigned* __restrict__ csrc,
    const unsigned long long* __restrict__ INb, const unsigned long long* __restrict__ B2b,
    const unsigned long long* __restrict__ Ab, const float* __restrict__ W,
    const float* __restrict__ ss, unsigned long long* __restrict__ OUT,
    float* __restrict__ partials) {
    constexpr int RU2 = FI / 4;                  // u64 per A row
    __shared__ float Wl[FI * 36];
    __shared__ float Atile[28][FI + 1];
    __shared__ float ls[72];
    int tid = threadIdx.x;                       // 252 threads = 28 rows x 9 lanes
    for (int i = tid; i < FI * 36; i += 252) Wl[i] = W[i];
    int r0 = blockIdx.x * 28;
    for (int i = tid; i < 28 * RU2; i += 252) {
        int r = i / RU2, u = i % RU2;
        int row = r0 + r;
        long long av = 0;
        if (row < N_NODES) {
            size_t idx = (FI == 64) ? ((size_t)row * 16 + u) : sidx(u, row);
            av = (long long)Ab[idx];
        }
        unsigned lo = (unsigned)av, hi = (unsigned)(av >> 32);
        float f0 = bflo(lo), f1 = bfhi(lo), f2 = bflo(hi), f3 = bfhi(hi);
        if (BN_A) {
            int f = u * 4;
            f0 = fmaxf(fmaf(ss[f + 0], f0, ss[36 + f + 0]), 0.f);
            f1 = fmaxf(fmaf(ss[f + 1], f1, ss[36 + f + 1]), 0.f);
            f2 = fmaxf(fmaf(ss[f + 2], f2, ss[36 + f + 2]), 0.f);
            f3 = fmaxf(fmaf(ss[f + 3], f3, ss[36 + f + 3]), 0.f);
        }
        Atile[r][u * 4 + 0] = f0; Atile[r][u * 4 + 1] = f1;
        Atile[r][u * 4 + 2] = f2; Atile[r][u * 4 + 3] = f3;
    }
    if (FUSE_STATS && tid < 72) ls[tid] = 0.f;
    __syncthreads();
    int r = tid / 9, c = tid % 9;
    int row = r0 + r;
    bool valid = row < N_NODES;
    // per-lane gather base/shift (branchless in loop)
    const unsigned long long* gb = INb + ((c < 8) ? (size_t)c : (size_t)N_NODES * 8);
    int gsh = (c < 8) ? 3 : 0;
    float ax = 0, ay = 0, az = 0, aw = 0;
    float bx = 0, by = 0, bz = 0, bw = 0;
    float cx = 0, cy = 0, cz = 0, cw = 0;
    float dx = 0, dy = 0, dz = 0, dw = 0;
    if (SCALE != 0 && valid) {
        int beg = rp[row], end = rp[row + 1];
        int j = beg;
        for (; j + 7 < end; j += 8) {
            unsigned v0 = csrc[j],     v1 = csrc[j + 1], v2 = csrc[j + 2], v3 = csrc[j + 3];
            unsigned v4 = csrc[j + 4], v5 = csrc[j + 5], v6 = csrc[j + 6], v7 = csrc[j + 7];
            unsigned long long q0 = gb[(size_t)esrc(v0) << gsh];
            unsigned long long q1 = gb[(size_t)esrc(v1) << gsh];
            unsigned long long q2 = gb[(size_t)esrc(v2) << gsh];
            unsigned long long q3 = gb[(size_t)esrc(v3) << gsh];
            unsigned long long q4 = gb[(size_t)esrc(v4) << gsh];
            unsigned long long q5 = gb[(size_t)esrc(v5) << gsh];
            unsigned long long q6 = gb[(size_t)esrc(v6) << gsh];
            unsigned long long q7 = gb[(size_t)esrc(v7) << gsh];
            float w0 = ew(v0), w1 = ew(v1), w2 = ew(v2), w3 = ew(v3);
            float w4 = ew(v4), w5 = ew(v5), w6 = ew(v6), w7 = ew(v7);
            unsigned l0 = (unsigned)q0, h0 = (unsigned)(q0 >> 32);
            unsigned l1 = (unsigned)q1, h1 = (unsigned)(q1 >> 32);
            unsigned l2 = (unsigned)q2, h2 = (unsigned)(q2 >> 32);
            unsigned l3 = (unsigned)q3, h3 = (unsigned)(q3 >> 32);
            unsigned l4 = (unsigned)q4, h4 = (unsigned)(q4 >> 32);
            unsigned l5 = (unsigned)q5, h5 = (unsigned)(q5 >> 32);
            unsigned l6 = (unsigned)q6, h6 = (unsigned)(q6 >> 32);
            unsigned l7 = (unsigned)q7, h7 = (unsigned)(q7 >> 32);
            ax = fmaf(w0, bflo(l0), ax); ay = fmaf(w0, bfhi(l0), ay);
            az = fmaf(w0, bflo(h0), az); aw = fmaf(w0, bfhi(h0), aw);
            bx = fmaf(w1, bflo(l1), bx); by = fmaf(w1, bfhi(l1), by);
            bz = fmaf(w1, bflo(h1), bz); bw = fmaf(w1, bfhi(h1), bw);
            cx = fmaf(w2, bflo(l2), cx); cy = fmaf(w2, bfhi(l2), cy);
            cz = fmaf(w2, bflo(h2), cz); cw = fmaf(w2, bfhi(h2), cw);
            dx = fmaf(w3, bflo(l3), dx); dy = fmaf(w3, bfhi(l3), dy);
            dz = fmaf(w3, bflo(h3), dz); dw = fmaf(w3, bfhi(h3), dw);
            ax = fmaf(w4, bflo(l4), ax); ay = fmaf(w4, bfhi(l4), ay);
            az = fmaf(w4, bflo(h4), az); aw = fmaf(w4, bfhi(h4), aw);
            bx = fmaf(w5, bflo(l5), bx); by = fmaf(w5, bfhi(l5), by);
            bz = fmaf(w5, bflo(h5), bz); bw = fmaf(w5, bfhi(h5), bw);
            cx = fmaf(w6, bflo(l6), cx); cy = fmaf(w6, bfhi(l6), cy);
            cz = fmaf(w6, bflo(h6), cz); cw = fmaf(w6, bfhi(h6), cw);
            dx = fmaf(w7, bflo(l7), dx); dy = fmaf(w7, bfhi(l7), dy);
            dz = fmaf(w7, bflo(h7), dz); dw = fmaf(w7, bfhi(h7), dw);
        }
        for (; j < end; ++j) {
            unsigned v = csrc[j];
            unsigned long long q = gb[(size_t)esrc(v) << gsh];
            float w = ew(v);
            unsigned l = (unsigned)q, h = (unsigned)(q >> 32);
            ax = fmaf(w, bflo(l), ax); ay = fmaf(w, bfhi(l), ay);
            az = fmaf(w, bflo(h), az); aw = fmaf(w, bfhi(h), aw);
        }
        ax += bx + cx + dx; ay += by + cy + dy;
        az += bz + cz + dz; aw += bw + cw + dw;
    }
    float px = 0, py = 0, pz = 0, pw = 0;
    const float4* Wl4 = (const float4*)Wl;
#pragma unroll 4
    for (int f = 0; f < FI; ++f) {
        float a = Atile[r][f];
        float4 wv = Wl4[f * 9 + c];
        px = fmaf(a, wv.x, px); py = fmaf(a, wv.y, py);
        pz = fmaf(a, wv.z, pz); pw = fmaf(a, wv.w, pw);
    }
    const float S = (float)SCALE;
    float4 o;
    o.x = fmaf(S, ax, px); o.y = fmaf(S, ay, py);
    o.z = fmaf(S, az, pz); o.w = fmaf(S, aw, pw);
    if (valid) {
        if (HAS_B2) {
            unsigned long long q = B2b[sidx(c, row)];
            unsigned l = (unsigned)q, h = (unsigned)(q >> 32);
            o.x -= bflo(l); o.y -= bfhi(l);
            o.z -= bflo(h); o.w -= bfhi(h);
        }
        unsigned long long pv = (unsigned long long)bf16pack(o.x, o.y)
                              | ((unsigned long long)bf16pack(o.z, o.w) << 32);
        OUT[sidx(c, row)] = pv;
        if (FUSE_STATS) {
            atomicAdd(&ls[c * 4 + 0], o.x); atomicAdd(&ls[36 + c * 4 + 0], o.x * o.x);
            atomicAdd(&ls[c * 4 + 1], o.y); atomicAdd(&ls[36 + c * 4 + 1], o.y * o.y);
            atomicAdd(&ls[c * 4 + 2], o.z); atomicAdd(&ls[36 + c * 4 + 2], o.z * o.z);
            atomicAdd(&ls[c * 4 + 3], o.w); atomicAdd(&ls[36 + c * 4 + 3], o.w * o.w);
        }
    }
    if (FUSE_STATS) {
        __syncthreads();
        if (tid < 72) partials[blockIdx.x * 72 + tid] = ls[tid];
    }
}

// ---------------- GIN gather (projection-first), split-layout ----------------

__global__ __launch_bounds__(256) void gin_gather_kernel(
    const int* __restrict__ rp, const unsigned* __restrict__ csrc,
    const unsigned long long* __restrict__ Yb, const float* __restrict__ b1,
    const float* __restrict__ w2, const float* __restrict__ b2,
    unsigned long long* __restrict__ OUT, float* __restrict__ partials) {
    __shared__ float W2l[36 * 36];
    __shared__ float B1l[36], B2l[36];
    __shared__ float M1t[28][37];
    __shared__ float ls[72];
    int tid = threadIdx.x;                       // 252 = 28 rows x 9 lanes
    for (int i = tid; i < 36 * 36; i += 252) W2l[i] = w2[i];
    if (tid < 36) { B1l[tid] = b1[tid]; B2l[tid] = b2[tid]; }
    if (tid < 72) ls[tid] = 0.f;
    __syncthreads();
    int r = tid / 9, c = tid % 9;
    int row = blockIdx.x * 28 + r;
    bool valid = row < N_NODES;
    const unsigned long long* gb = Yb + ((c < 8) ? (size_t)c : (size_t)N_NODES * 8);
    int gsh = (c < 8) ? 3 : 0;
    float ax = 0, ay = 0, az = 0, aw = 0;
    float bx = 0, by = 0, bz = 0, bw = 0;
    float cx = 0, cy = 0, cz = 0, cw = 0;
    float dx = 0, dy = 0, dz = 0, dw = 0;
    if (valid) {
        unsigned long long qs = Yb[sidx(c, row)];
        unsigned lsf = (unsigned)qs, hsf = (unsigned)(qs >> 32);
        ax = bflo(lsf); ay = bfhi(lsf); az = bflo(hsf); aw = bfhi(hsf);
        int beg = rp[row], end = rp[row + 1];
        int j = beg;
        for (; j + 7 < end; j += 8) {
            unsigned long long q0 = gb[(size_t)esrc(csrc[j])     << gsh];
            unsigned long long q1 = gb[(size_t)esrc(csrc[j + 1]) << gsh];
            unsigned long long q2 = gb[(size_t)esrc(csrc[j + 2]) << gsh];
            unsigned long long q3 = gb[(size_t)esrc(csrc[j + 3]) << gsh];
            unsigned long long q4 = gb[(size_t)esrc(csrc[j + 4]) << gsh];
            unsigned long long q5 = gb[(size_t)esrc(csrc[j + 5]) << gsh];
            unsigned long long q6 = gb[(size_t)esrc(csrc[j + 6]) << gsh];
            unsigned long long q7 = gb[(size_t)esrc(csrc[j + 7]) << gsh];
            unsigned l0 = (unsigned)q0, h0 = (unsigned)(q0 >> 32);
            unsigned l1 = (unsigned)q1, h1 = (unsigned)(q1 >> 32);
            unsigned l2 = (unsigned)q2, h2 = (unsigned)(q2 >> 32);
            unsigned l3 = (unsigned)q3, h3 = (unsigned)(q3 >> 32);
            unsigned l4 = (unsigned)q4, h4 = (unsigned)(q4 >> 32);
            unsigned l5 = (unsigned)q5, h5 = (unsigned)(q5 >> 32);
            unsigned l6 = (unsigned)q6, h6 = (unsigned)(q6 >> 32);
            unsigned l7 = (unsigned)q7, h7 = (unsigned)(q7 >> 32);
            ax += bflo(l0) + bflo(l4); ay += bfhi(l0) + bfhi(l4);
            az += bflo(h0) + bflo(h4); aw += bfhi(h0) + bfhi(h4);
            bx += bflo(l1) + bflo(l5); by += bfhi(l1) + bfhi(l5);
            bz += bflo(h1) + bflo(h5); bw += bfhi(h1) + bfhi(h5);
            cx += bflo(l2) + bflo(l6); cy += bfhi(l2) + bfhi(l6);
            cz += bflo(h2) + bflo(h6); cw += bfhi(h2) + bfhi(h6);
            dx += bflo(l3) + bflo(l7); dy += bfhi(l3) + bfhi(l7);
            dz += bflo(h3) + bflo(h7); dw += bfhi(h3) + bfhi(h7);
        }
        for (; j < end; ++j) {
            unsigned long long q = gb[(size_t)esrc(csrc[j]) << gsh];
            unsigned l = (unsigned)q, h = (unsigned)(q >> 32);
            ax += bflo(l); ay += bfhi(l);
            az += bflo(h); aw += bfhi(h);
        }
        ax += bx + cx + dx; ay += by + cy + dy;
        az += bz + cz + dz; aw += bw + cw + dw;
    }
    float m0 = fmaxf(ax + B1l[c * 4 + 0], 0.f);
    float m1 = fmaxf(ay + B1l[c * 4 + 1], 0.f);
    float m2 = fmaxf(az + B1l[c * 4 + 2], 0.f);
    float m3 = fmaxf(aw + B1l[c * 4 + 3], 0.f);
    M1t[r][c * 4 + 0] = m0; M1t[r][c * 4 + 1] = m1;
    M1t[r][c * 4 + 2] = m2; M1t[r][c * 4 + 3] = m3;
    __syncthreads();
    float o0 = B2l[c * 4 + 0], o1 = B2l[c * 4 + 1];
    float o2 = B2l[c * 4 + 2], o3 = B2l[c * 4 + 3];
    const float4* W2l4 = (const float4*)W2l;
#pragma unroll 4
    for (int f = 0; f < 36; ++f) {
        float a = M1t[r][f];
        float4 wv = W2l4[f * 9 + c];
        o0 = fmaf(a, wv.x, o0); o1 = fmaf(a, wv.y, o1);
        o2 = fmaf(a, wv.z, o2); o3 = fmaf(a, wv.w, o3);
    }
    o0 = fmaxf(o0, 0.f); o1 = fmaxf(o1, 0.f);
    o2 = fmaxf(o2, 0.f); o3 = fmaxf(o3, 0.f);
    if (valid) {
        unsigned long long pv = (unsigned long long)bf16pack(o0, o1)
                              | ((unsigned long long)bf16pack(o2, o3) << 32);
        OUT[sidx(c, row)] = pv;
        atomicAdd(&ls[c * 4 + 0], o0); atomicAdd(&ls[36 + c * 4 + 0], o0 * o0);
        atomicAdd(&ls[c * 4 + 1], o1); atomicAdd(&ls[36 + c * 4 + 1], o1 * o1);
        atomicAdd(&ls[c * 4 + 2], o2); atomicAdd(&ls[36 + c * 4 + 2], o2 * o2);
        atomicAdd(&ls[c * 4 + 3], o3); atomicAdd(&ls[36 + c * 4 + 3], o3 * o3);
    }
    __syncthreads();
    if (tid < 72) partials[blockIdx.x * 72 + tid] = ls[tid];
}

// ---------------- finalize: reduce partials -> BN scale/shift ----------------

__global__ __launch_bounds__(256) void finalize_kernel(
    const float* __restrict__ partials, int nb, const float* __restrict__ g,
    const float* __restrict__ be, float* __restrict__ ss) {
    __shared__ float rs[256], rq[256];
    int c = blockIdx.x;
    int t = threadIdx.x;
    float s = 0.f, q = 0.f;
    for (int i = t; i < nb; i += 256) {
        s += partials[i * 72 + c];
        q += partials[i * 72 + c + 36];
    }
    rs[t] = s; rq[t] = q;
    __syncthreads();
    for (int off = 128; off > 0; off >>= 1) {
        if (t < off) { rs[t] += rs[t + off]; rq[t] += rq[t + off]; }
        __syncthreads();
    }
    if (t == 0) {
        float m = rs[0] / (float)N_NODES;
        float v = rq[0] / (float)N_NODES - m * m;
        float sc = g[c] * rsqrtf(v + 1e-5f);
        ss[c] = sc;
        ss[36 + c] = be[c] - m * sc;
    }
}

// ---------------- final concat GEMM, split-layout bf16 inputs (32 rows/block) ----

__global__ __launch_bounds__(256) void fused3_kernel(
    const unsigned long long* __restrict__ X1b, const float* __restrict__ ssA,
    const unsigned long long* __restrict__ X2b, const float* __restrict__ ssB,
    const unsigned long long* __restrict__ X3b, const float* __restrict__ ssC,
    const float* __restrict__ W, const float* __restrict__ b,
    float* __restrict__ out) {
    __shared__ float Wl[108 * 32];
    __shared__ float Al[32][109];
    int tid = threadIdx.x;
    for (int i = tid; i < 108 * 32; i += 256) Wl[i] = W[i];
    int r0 = blockIdx.x * 32;
    for (int i = tid; i < 32 * 108; i += 256) {
        int r = i / 108, f = i % 108;
        int row = r0 + r;
        float v = 0.f;
        if (row < N_NODES) {
            int t = f / 36, ff = f % 36;
            const unsigned short* b16 =
                (const unsigned short*)(t == 0 ? X1b : (t == 1 ? X2b : X3b));
            unsigned short u16 = (ff < 32)
                ? b16[(size_t)row * 32 + ff]
                : b16[(size_t)N_NODES * 32 + (size_t)row * 4 + (ff - 32)];
            float xv = __uint_as_float((unsigned)u16 << 16);
            if (t == 0)      v = fmaxf(fmaf(ssA[ff], xv, ssA[36 + ff]), 0.f);
            else if (t == 1) v = fmaxf(fmaf(ssB[ff], xv, ssB[36 + ff]), 0.f);
            else             v = fmaf(ssC[ff], xv, ssC[36 + ff]);
        }
        Al[r][f] = v;
    }
    __syncthreads();
    int r = tid >> 3, q = tid & 7;
    int row = r0 + r;
    if (row >= N_NODES) return;
    float acc[4];
#pragma unroll
    for (int j = 0; j < 4; ++j) acc[j] = b[q * 4 + j];
    for (int f = 0; f < 108; ++f) {
        float a = Al[r][f];
#pragma unroll
        for (int j = 0; j < 4; ++j)
            acc[j] = fmaf(a, Wl[f * 32 + q * 4 + j], acc[j]);
    }
#pragma unroll
    for (int j = 0; j < 4; ++j) out[(size_t)row * 32 + q * 4 + j] = acc[j];
}

// ---------------- launch ----------------

extern "C" void kernel_launch(void* const* d_in, const int* in_sizes, int n_in,
                              void* d_out, int out_size, void* d_ws, size_t ws_size,
                              hipStream_t stream) {
    const float* x      = (const float*)d_in[0];
    const int*   ei     = (const int*)d_in[1];
    const float* W1_1   = (const float*)d_in[2];
    // b1_1 / b1_2 cancel exactly under training-mode BN -> dropped.
    const float* g1_1   = (const float*)d_in[4];
    const float* be1_1  = (const float*)d_in[5];
    const float* W1_2   = (const float*)d_in[6];
    const float* g1_2   = (const float*)d_in[8];
    const float* be1_2  = (const float*)d_in[9];
    const float* gin_w1 = (const float*)d_in[10];
    const float* gin_b1 = (const float*)d_in[11];
    const float* gin_w2 = (const float*)d_in[12];
    const float* gin_b2 = (const float*)d_in[13];
    const float* g2     = (const float*)d_in[14];
    const float* be2    = (const float*)d_in[15];
    const float* W4     = (const float*)d_in[16];
    const float* b4     = (const float*)d_in[17];
    float* out = (float*)d_out;

    char* ws = (char*)d_ws;
    size_t off = 0;
    auto alloc = [&](size_t bytes) -> char* {
        char* p = ws + off;
        off = (off + bytes + 255) & ~(size_t)255;
        return p;
    };
    int*   cntD  = (int*)alloc((size_t)LCNT * 4);
    int*   cntS  = (int*)alloc((size_t)LCNT * 4);
    int*   bsum  = (int*)alloc(1024 * 4);
    int*   rp    = (int*)alloc((size_t)(N_NODES + 1) * 4);
    float* dis   = (float*)alloc((size_t)N_NODES * 4);
    int2*  edgepart = (int2*)alloc((size_t)N_EDGES * 8);
    int*   srcpart  = (int*)alloc((size_t)N_EDGES * 4);
    unsigned* csrc = (unsigned*)alloc((size_t)N_EDGES * 4);
    float* ssA   = (float*)alloc(72 * 4);
    float* ssB   = (float*)alloc(72 * 4);
    float* ssC   = (float*)alloc(72 * 4);
    float* partials = (float*)alloc((size_t)6250 * 72 * 4);
    constexpr size_t NBBF = (size_t)N_NODES * 72;          // split: 6.4MB A + 0.8MB B
    uint2* xbf = (uint2*)alloc((size_t)N_NODES * 128);     // bf16 [N,64] 128B rows
    unsigned long long* R0  = (unsigned long long*)alloc(NBBF);
    unsigned long long* R1  = (unsigned long long*)alloc(NBBF);
    unsigned long long* R2  = (unsigned long long*)alloc(NBBF);
    unsigned long long* X1b = (unsigned long long*)alloc(NBBF);
    unsigned long long* X2b = (unsigned long long*)alloc(NBBF);
    unsigned long long* X3b = (unsigned long long*)alloc(NBBF);
    if (off > ws_size) return;

    // ---- preprocessing: counting-sort CSR build (no global atomics) ----
    part_count_kernel<<<NBLK, 256, 0, stream>>>(ei, cntD, cntS);
    scanA_kernel<<<SCAN_BLKS, 256, 0, stream>>>(cntD, cntD, bsum, LCNT);
    scanB_kernel<<<1, 1024, 0, stream>>>(bsum, SCAN_BLKS);
    scanC_kernel<<<SCAN_BLKS, 256, 0, stream>>>(cntD, bsum, LCNT);
    scanA_kernel<<<SCAN_BLKS, 256, 0, stream>>>(cntS, cntS, bsum, LCNT);
    scanB_kernel<<<1, 1024, 0, stream>>>(bsum, SCAN_BLKS);
    scanC_kernel<<<SCAN_BLKS, 256, 0, stream>>>(cntS, bsum, LCNT);
    part_scatter_kernel<<<NBLK, 256, 0, stream>>>(ei, cntD, cntS, edgepart, srcpart);
    deg_kernel<<<NBK, 256, 0, stream>>>(srcpart, cntS, dis);
    csr_kernel<<<NBK, 256, 0, stream>>>(edgepart, cntD, dis, rp, csrc);
    pack_x_kernel<<<(N_NODES * 16 + 255) / 256, 256, 0, stream>>>(x, xbf);

    const int STEP_BLKS = (N_NODES + 27) / 28;        // 3572
    const int F3_BLKS   = (N_NODES + 31) / 32;        // 3125
    const unsigned long long* xb64 = (const unsigned long long*)xbf;

    // ---- conv1_1 (Clenshaw, FI=64, A=xbf) ----
    cheb_step_kernel<64, 0, false, false, false><<<STEP_BLKS, 252, 0, stream>>>(
        rp, csrc, nullptr, nullptr, xb64, W1_1 + 7 * 2304, nullptr, R0, nullptr);
    cheb_step_kernel<64, 2, false, false, false><<<STEP_BLKS, 252, 0, stream>>>(
        rp, csrc, R0, nullptr, xb64, W1_1 + 6 * 2304, nullptr, R1, nullptr);
    cheb_step_kernel<64, 2, true, false, false><<<STEP_BLKS, 252, 0, stream>>>(
        rp, csrc, R1, R0, xb64, W1_1 + 5 * 2304, nullptr, R2, nullptr);
    cheb_step_kernel<64, 2, true, false, false><<<STEP_BLKS, 252, 0, stream>>>(
        rp, csrc, R2, R1, xb64, W1_1 + 4 * 2304, nullptr, R0, nullptr);
    cheb_step_kernel<64, 2, true, false, false><<<STEP_BLKS, 252, 0, stream>>>(
        rp, csrc, R0, R2, xb64, W1_1 + 3 * 2304, nullptr, R1, nullptr);
    cheb_step_kernel<64, 2, true, false, false><<<STEP_BLKS, 252, 0, stream>>>(
        rp, csrc, R1, R0, xb64, W1_1 + 2 * 2304, nullptr, R2, nullptr);
    cheb_step_kernel<64, 2, true, false, false><<<STEP_BLKS, 252, 0, stream>>>(
        rp, csrc, R2, R1, xb64, W1_1 + 1 * 2304, nullptr, R0, nullptr);
    cheb_step_kernel<64, 1, true, false, true><<<STEP_BLKS, 252, 0, stream>>>(
        rp, csrc, R0, R2, xb64, W1_1 + 0 * 2304, nullptr, X1b, partials);
    finalize_kernel<<<36, 256, 0, stream>>>(partials, STEP_BLKS, g1_1, be1_1, ssA);

    // ---- conv1_2 (Clenshaw, FI=36, A=X1b with BN ssA) ----
    cheb_step_kernel<36, 0, false, true, false><<<STEP_BLKS, 252, 0, stream>>>(
        rp, csrc, nullptr, nullptr, X1b, W1_2 + 7 * 1296, ssA, R0, nullptr);
    cheb_step_kernel<36, 2, false, true, false><<<STEP_BLKS, 252, 0, stream>>>(
        rp, csrc, R0, nullptr, X1b, W1_2 + 6 * 1296, ssA, R1, nullptr);
    cheb_step_kernel<36, 2, true, true, false><<<STEP_BLKS, 252, 0, stream>>>(
        rp, csrc, R1, R0, X1b, W1_2 + 5 * 1296, ssA, R2, nullptr);
    cheb_step_kernel<36, 2, true, true, false><<<STEP_BLKS, 252, 0, stream>>>(
        rp, csrc, R2, R1, X1b, W1_2 + 4 * 1296, ssA, R0, nullptr);
    cheb_step_kernel<36, 2, true, true, false><<<STEP_BLKS, 252, 0, stream>>>(
        rp, csrc, R0, R2, X1b, W1_2 + 3 * 1296, ssA, R1, nullptr);
    cheb_step_kernel<36, 2, true, true, false><<<STEP_BLKS, 252, 0, stream>>>(
        rp, csrc, R1, R0, X1b, W1_2 + 2 * 1296, ssA, R2, nullptr);
    cheb_step_kernel<36, 2, true, true, false><<<STEP_BLKS, 252, 0, stream>>>(
        rp, csrc, R2, R1, X1b, W1_2 + 1 * 1296, ssA, R0, nullptr);
    cheb_step_kernel<36, 1, true, true, true><<<STEP_BLKS, 252, 0, stream>>>(
        rp, csrc, R0, R2, X1b, W1_2 + 0 * 1296, ssA, X2b, partials);
    finalize_kernel<<<36, 256, 0, stream>>>(partials, STEP_BLKS, g1_2, be1_2, ssB);

    // ---- GIN (projection-first: y = x@gin_w1 from xbf, then 36-wide gather) ----
    cheb_step_kernel<64, 0, false, false, false><<<STEP_BLKS, 252, 0, stream>>>(
        rp, csrc, nullptr, nullptr, xb64, gin_w1, nullptr, R0, nullptr);
    gin_gather_kernel<<<STEP_BLKS, 252, 0, stream>>>(rp, csrc, R0, gin_b1,
                                                     gin_w2, gin_b2, X3b, partials);
    finalize_kernel<<<36, 256, 0, stream>>>(partials, STEP_BLKS, g2, be2, ssC);

    // ---- final concat GEMM ----
    fused3_kernel<<<F3_BLKS, 256, 0, stream>>>(X1b, ssA, X2b, ssB, X3b, ssC, W4, b4, out);
}